// Round 13
// baseline (87937.042 us; speedup 1.0000x reference)
//
#include <hip/hip_runtime.h>
#include <cstdint>
#include <cmath>

#define DEVI __device__ __forceinline__

constexpr int B_ = 16, TENC_ = 168, TBERT_ = 96, TOUT_ = 200;
constexpr int NMEL_ = 80, ENC_ = 512, ARNN_ = 1024, PRE_ = 256, ATT_ = 128, NF_ = 32, KCV_ = 31;

// ---------------- workspace layout (float offsets) ----------------
constexpr size_t o_qWTa = 0;
constexpr size_t o_qWTb = o_qWTa + 1024*128;
constexpr size_t o_pall  = o_qWTb + 1024*128;              // [T][16][256]
constexpr size_t o_pball = o_pall + (size_t)TOUT_*B_*PRE_;
constexpr size_t o_pmem  = o_pball + (size_t)TOUT_*B_*PRE_;
constexpr size_t o_pbert = o_pmem + (size_t)B_*TENC_*ATT_;
constexpr size_t o_state = o_pbert + (size_t)B_*TBERT_*ATT_;
constexpr size_t o_ah   = o_state;            // [2][16][1024]
constexpr size_t o_ahb  = o_ah  + 32768;
constexpr size_t o_ac   = o_ahb + 32768;      // [2][1024][16]  (double-buffered!)
constexpr size_t o_acb  = o_ac  + 32768;
constexpr size_t o_dh   = o_acb + 32768;      // [16][1024]
constexpr size_t o_dc   = o_dh  + 16384;      // [1024][16]
constexpr size_t o_dhb  = o_dc  + 16384;
constexpr size_t o_dcb  = o_dhb + 16384;
constexpr size_t o_ctx  = o_dcb + 16384;      // [16][512]
constexpr size_t o_ctxb = o_ctx + 8192;
constexpr size_t o_aw   = o_ctxb+ 8192;
constexpr size_t o_awc  = o_aw  + 2688;
constexpr size_t o_awb  = o_awc + 2688;
constexpr size_t o_awcb = o_awb + 1536;
constexpr size_t o_zend = o_awcb+ 1536;
constexpr size_t ZCOUNT = o_zend - o_state;
constexpr size_t o_ga   = o_zend;             // [4096][16] gates (row = gate*1024+u)
constexpr size_t o_gab  = o_ga  + 65536;
constexpr size_t o_gd   = o_gab + 65536;
constexpr size_t o_gdb  = o_gd  + 65536;
constexpr size_t o_dhall   = o_gdb + 65536;
constexpr size_t o_ctxall  = o_dhall + (size_t)TOUT_*B_*ARNN_;
constexpr size_t o_ctxball = o_ctxall + (size_t)TOUT_*B_*ENC_;
constexpr size_t o_bar     = o_ctxball + (size_t)TOUT_*B_*ENC_;  // 8320 ints
// packed weights per type: [rg(512)][kg][8r][8ks][4j]
constexpr int KG0 = 56, KG2 = 128, KG3 = 80;   // K/32 per type (1792/4096/2560)
constexpr size_t o_pkA  = o_bar + 8320;
constexpr size_t o_pkB  = o_pkA + (size_t)512*KG0*256;
constexpr size_t o_pkD  = o_pkB + (size_t)512*KG0*256;
constexpr size_t o_pkDB = o_pkD + (size_t)512*KG2*256;
constexpr size_t o_pkend= o_pkDB + (size_t)512*KG3*256;

// output offsets (floats)
constexpr size_t OO_MEL  = 0;
constexpr size_t OO_GATE = (size_t)B_*NMEL_*TOUT_;
constexpr size_t OO_AL   = OO_GATE + (size_t)B_*TOUT_;
constexpr size_t OO_ALB  = OO_AL + (size_t)B_*TOUT_*TENC_;

DEVI float sigf(float x) { return 1.f / (1.f + expf(-x)); }

DEVI float dotseg(const float* __restrict__ w, const float* __restrict__ x, int n) {
  const float4* wp = reinterpret_cast<const float4*>(w);
  const float4* xp = reinterpret_cast<const float4*>(x);
  float a0 = 0, a1 = 0, a2 = 0, a3 = 0;
  int n4 = n >> 2;
#pragma unroll 4
  for (int i = 0; i < n4; ++i) {
    float4 wv = wp[i], xv = xp[i];
    a0 = fmaf(wv.x, xv.x, a0); a1 = fmaf(wv.y, xv.y, a1);
    a2 = fmaf(wv.z, xv.z, a2); a3 = fmaf(wv.w, xv.w, a3);
  }
  return (a0 + a1) + (a2 + a3);
}

// ======== grid barrier (256 blocks): per-block flag lines + block0 collector ========
DEVI void gridbar(int* flags, int* gen, int tgt) {
  __syncthreads();
  if (blockIdx.x == 0) {
    int i = threadIdx.x;
    if (i >= 1 && i < 256) {
      while (__hip_atomic_load(flags + i*32, __ATOMIC_RELAXED, __HIP_MEMORY_SCOPE_AGENT) < tgt)
        __builtin_amdgcn_s_sleep(8);
    }
    __syncthreads();
    __threadfence();
    if (threadIdx.x == 0)
      __hip_atomic_store(gen, tgt, __ATOMIC_RELEASE, __HIP_MEMORY_SCOPE_AGENT);
    __syncthreads();
  } else {
    if (threadIdx.x == 0) {
      __threadfence();
      __hip_atomic_store(flags + blockIdx.x*32, tgt, __ATOMIC_RELEASE, __HIP_MEMORY_SCOPE_AGENT);
      while (__hip_atomic_load(gen, __ATOMIC_RELAXED, __HIP_MEMORY_SCOPE_AGENT) < tgt)
        __builtin_amdgcn_s_sleep(8);
      __threadfence();
    }
    __syncthreads();
  }
}

// ================= prolog =================
__global__ __launch_bounds__(256) void k_prolog(
    const float* __restrict__ dec, const float* __restrict__ pw1, const float* __restrict__ pw2,
    const float* __restrict__ pbw1, const float* __restrict__ pbw2,
    const float* __restrict__ memory, const float* __restrict__ embeddings,
    const float* __restrict__ am, const float* __restrict__ abm,
    const float* __restrict__ aq, const float* __restrict__ abq,
    const float* __restrict__ a_wih, const float* __restrict__ a_whh,
    const float* __restrict__ ab_wih, const float* __restrict__ ab_whh,
    const float* __restrict__ d_wih, const float* __restrict__ d_whh,
    const float* __restrict__ db_wih, const float* __restrict__ db_whh,
    int packed, float* __restrict__ ws)
{
  __shared__ float smem[10240];
  int bid = blockIdx.x, tid = threadIdx.x;
  if (bid < 200) {
    int t = bid;
    float* xl  = smem;
    float* h1  = smem + 1280;
    float* h1b = smem + 1280 + 4096;
    for (int i = tid; i < 16*80; i += 256) {
      int b = i / 80, m = i % 80;
      xl[i] = (t == 0) ? 0.f : dec[((size_t)b*80 + m)*200 + (t-1)];
    }
    __syncthreads();
    int j = tid;
    for (int b = 0; b < 16; ++b) {
      const float* x = xl + b*80;
      float a1 = 0, a2 = 0;
#pragma unroll 4
      for (int m = 0; m < 80; ++m) { a1 = fmaf(pw1[j*80+m], x[m], a1); a2 = fmaf(pbw1[j*80+m], x[m], a2); }
      h1[b*256+j]  = fmaxf(a1, 0.f);
      h1b[b*256+j] = fmaxf(a2, 0.f);
    }
    __syncthreads();
    for (int b = 0; b < 16; ++b) {
      float a1 = 0, a2 = 0;
#pragma unroll 4
      for (int k = 0; k < 256; ++k) { a1 = fmaf(pw2[j*256+k], h1[b*256+k], a1); a2 = fmaf(pbw2[j*256+k], h1b[b*256+k], a2); }
      ws[o_pall  + ((size_t)t*16+b)*256 + j] = fmaxf(a1, 0.f);
      ws[o_pball + ((size_t)t*16+b)*256 + j] = fmaxf(a2, 0.f);
    }
  } else if (bid < 368) {
    int r0 = (bid - 200) * 16;
    float* ml = smem;
    for (int i = tid; i < 16*512; i += 256) ml[i] = memory[(size_t)r0*512 + i];
    __syncthreads();
    int a = tid & 127, ro = tid >> 7;
    for (int row = ro; row < 16; row += 2) {
      const float* x = ml + row*512; const float* w = am + (size_t)a*512;
      float acc = 0;
#pragma unroll 4
      for (int e = 0; e < 512; ++e) acc = fmaf(w[e], x[e], acc);
      ws[o_pmem + (size_t)(r0+row)*128 + a] = acc;
    }
  } else if (bid < 464) {
    int r0 = (bid - 368) * 16;
    float* ml = smem;
    for (int i = tid; i < 16*512; i += 256) ml[i] = embeddings[(size_t)r0*512 + i];
    __syncthreads();
    int a = tid & 127, ro = tid >> 7;
    for (int row = ro; row < 16; row += 2) {
      const float* x = ml + row*512; const float* w = abm + (size_t)a*512;
      float acc = 0;
#pragma unroll 4
      for (int e = 0; e < 512; ++e) acc = fmaf(w[e], x[e], acc);
      ws[o_pbert + (size_t)(r0+row)*128 + a] = acc;
    }
  } else if (bid < 466) {
    const float* src = (bid == 464) ? aq : abq;
    float* dst = ws + ((bid == 464) ? o_qWTa : o_qWTb);
    for (int i = tid; i < 1024*128; i += 256) {
      int k = i >> 7, a = i & 127;
      dst[i] = src[(size_t)a*1024 + k];
    }
  } else if (bid < 474) {
    int zi = bid - 466;
    for (size_t i = (size_t)zi*256 + tid; i < ZCOUNT; i += 8*256) ws[o_state + i] = 0.f;
  } else if (bid < 475) {
    int* bars = (int*)(ws + o_bar);
    for (int i = tid; i < 8320; i += 256) bars[i] = 0;
  } else {
    // weight repack: pk[type][rg][kg][r(8)][ks(8)][j(4)]
    if (!packed) return;
    int pbid = bid - 475;        // 0..511
    int type = pbid >> 7, idx = pbid & 127;
    const float *Wih, *Whh; int IH, C; float* dst;
    switch (type) {
      case 0:  Wih = a_wih;  Whh = a_whh;  IH = 768;  C = KG0; dst = ws + o_pkA;  break;
      case 1:  Wih = ab_wih; Whh = ab_whh; IH = 768;  C = KG0; dst = ws + o_pkB;  break;
      case 2:  Wih = d_wih;  Whh = d_whh;  IH = 3072; C = KG2; dst = ws + o_pkD;  break;
      default: Wih = db_wih; Whh = db_whh; IH = 1536; C = KG3; dst = ws + o_pkDB; break;
    }
    for (int q = 0; q < 4; ++q) {
      int rg = idx*4 + q;
      float* d = dst + (size_t)rg * C * 256;
      int tot = C * 256;
      for (int flat = tid; flat < tot; flat += 256) {
        int kg = flat >> 8, e = flat & 255;
        int r = e >> 5, ks = (e >> 2) & 7, j = e & 3;
        int row = rg*8 + r;
        int k = kg*32 + ks*4 + j;
        d[flat] = (k < IH) ? Wih[(size_t)row*IH + k] : Whh[(size_t)row*1024 + (k - IH)];
      }
    }
  }
}

// ================= persistent kernel =================
// Phase A: wave owns 8 rows x full K. lane=(r,ks): acc[16] (one per batch),
// 1KB coalesced packed w loads, x direct from global (L2), shuffle k-reduce.
// No LDS, no barriers in phase A. All gates -> global; pointwise in phase B.
__global__ __launch_bounds__(512, 2) void k_persist(
    const float* __restrict__ memory, const float* __restrict__ embeddings,
    const float* __restrict__ a_wih, const float* __restrict__ a_whh, const float* __restrict__ a_b,
    const float* __restrict__ ab_wih, const float* __restrict__ ab_whh, const float* __restrict__ ab_b,
    const float* __restrict__ d_wih, const float* __restrict__ d_whh, const float* __restrict__ d_b,
    const float* __restrict__ db_wih, const float* __restrict__ db_whh, const float* __restrict__ db_b,
    const float* __restrict__ a_conv, const float* __restrict__ a_loc, const float* __restrict__ a_v,
    const float* __restrict__ ab_conv, const float* __restrict__ ab_loc, const float* __restrict__ ab_v,
    int packed, float* __restrict__ ws, float* __restrict__ out)
{
  __shared__ __align__(16) float dlds[10240];   // phase-B attention scratch only
  int bid = blockIdx.x, tid = threadIdx.x;
  int wv = tid >> 6, lane = tid & 63;
  int r = lane >> 3, ks = lane & 7;
  int* bflags = (int*)(ws + o_bar);
  int* bgen = bflags + 8192;
  int bcnt = 0;

  // wave -> type; SIMD s hosts waves {s, s+4}: pairs (0,3),(1,2),(2,1),(3,0)
  const int tmap[8] = {0, 1, 2, 3, 3, 2, 1, 0};
  int type = tmap[wv];
  int inst = wv >> 2;
  int rg = inst*256 + bid;         // 0..511 per type
  int row0 = rg * 8;

  int IH, KG; const float *Wih, *Whh; const float* pkw0; float* gout;
  switch (type) {
    case 0:  IH = 768;  KG = KG0; Wih = a_wih;  Whh = a_whh;  pkw0 = ws + o_pkA;  gout = ws + o_ga;  break;
    case 1:  IH = 768;  KG = KG0; Wih = ab_wih; Whh = ab_whh; pkw0 = ws + o_pkB;  gout = ws + o_gab; break;
    case 2:  IH = 3072; KG = KG2; Wih = d_wih;  Whh = d_whh;  pkw0 = ws + o_pkD;  gout = ws + o_gd;  break;
    default: IH = 1536; KG = KG3; Wih = db_wih; Whh = db_whh; pkw0 = ws + o_pkDB; gout = ws + o_gdb; break;
  }
  pkw0 += (size_t)rg * KG * 256;

  for (int t = 0; t <= TOUT_; ++t) {
    bool act = (type < 2) ? (t < TOUT_) : (t >= 1);
    int par = (t + 1) & 1;    // parity of h/c state read this step

    if (act) {
      // x segment list (lengths in kg units of 32 floats)
      const float* sb[5]; int sstr[5], sn[5]; int nseg;
      if (type < 2) {
        sb[0] = ws + (type ? o_pball : o_pall) + (size_t)t*4096; sstr[0] = 256;  sn[0] = 8;
        sb[1] = ws + (type ? o_ctxb : o_ctx);                    sstr[1] = 512;  sn[1] = 16;
        sb[2] = ws + (type ? o_ahb : o_ah) + (size_t)par*16384;  sstr[2] = 1024; sn[2] = 32;
        nseg = 3;
      } else if (type == 2) {
        sb[0] = ws + o_ah  + (size_t)par*16384; sstr[0] = 1024; sn[0] = 32;
        sb[1] = ws + o_ahb + (size_t)par*16384; sstr[1] = 1024; sn[1] = 32;
        sb[2] = ws + o_ctx;                     sstr[2] = 512;  sn[2] = 16;
        sb[3] = ws + o_ctxb;                    sstr[3] = 512;  sn[3] = 16;
        sb[4] = ws + o_dh;                      sstr[4] = 1024; sn[4] = 32;
        nseg = 5;
      } else {
        sb[0] = ws + o_ahb + (size_t)par*16384; sstr[0] = 1024; sn[0] = 32;
        sb[1] = ws + o_ctxb;                    sstr[1] = 512;  sn[1] = 16;
        sb[2] = ws + o_dhb;                     sstr[2] = 1024; sn[2] = 32;
        nseg = 3;
      }

      float acc[16];
#pragma unroll
      for (int b = 0; b < 16; ++b) acc[b] = 0.f;

      auto wload = [&](int kgi) -> float4 {
        if (packed) return *(const float4*)(pkw0 + (size_t)kgi*256 + lane*4);
        int k = kgi*32 + ks*4;
        int row = row0 + r;
        const float* p = (k < IH) ? Wih + (size_t)row*IH + k
                                  : Whh + (size_t)row*1024 + (k - IH);
        return *(const float4*)p;
      };

      int kg = 0;
      float4 wc = wload(0);
      for (int s = 0; s < nseg; ++s) {
        const float* xb0 = sb[s] + ks*4;
        int str = sstr[s];
        for (int i = 0; i < sn[s]; ++i) {
          float4 wn = wc;
          if (kg + 1 < KG) wn = wload(kg + 1);
          const float* xb = xb0 + i*32;
#pragma unroll
          for (int b = 0; b < 16; ++b) {
            float4 xv = *(const float4*)(xb + b*str);
            acc[b] = fmaf(wc.x, xv.x, acc[b]);
            acc[b] = fmaf(wc.y, xv.y, acc[b]);
            acc[b] = fmaf(wc.z, xv.z, acc[b]);
            acc[b] = fmaf(wc.w, xv.w, acc[b]);
          }
          wc = wn; ++kg;
        }
      }
      // k-reduce across the 8 ks lanes of this row group
#pragma unroll
      for (int b = 0; b < 16; ++b) {
        acc[b] += __shfl_xor(acc[b], 1);
        acc[b] += __shfl_xor(acc[b], 2);
        acc[b] += __shfl_xor(acc[b], 4);
      }
      // lane (r,ks) writes b = 2ks, 2ks+1 (static-index select)
      float v0 = acc[0], v1 = acc[1];
#pragma unroll
      for (int bb = 1; bb < 8; ++bb)
        if (ks == bb) { v0 = acc[2*bb]; v1 = acc[2*bb + 1]; }
      float2 v; v.x = v0; v.y = v1;
      *(float2*)(gout + (size_t)(row0 + r)*16 + 2*ks) = v;
    }
    gridbar(bflags, bgen, ++bcnt);

    // ---------------- phase B ----------------
    if (bid < 32) {
      if (t < TOUT_) {
        bool isB = bid >= 16; int b = bid & 15;
        int T = isB ? TBERT_ : TENC_;
        const float* mem   = isB ? embeddings : memory;
        const float* pmemB = ws + (isB ? o_pbert : o_pmem);
        const float* qWT   = ws + (isB ? o_qWTb : o_qWTa);
        const float* convW = isB ? ab_conv : a_conv;
        const float* locW  = isB ? ab_loc : a_loc;
        const float* vW    = isB ? ab_v : a_v;
        float* awS  = ws + (isB ? o_awb : o_aw) + (size_t)b*T;
        float* awcS = ws + (isB ? o_awcb : o_awc) + (size_t)b*T;
        float* ctxS = ws + (isB ? o_ctxb : o_ctx) + (size_t)b*ENC_;
        float* ctxAll = ws + (isB ? o_ctxball : o_ctxall) + ((size_t)t*16 + b)*ENC_;
        float* alOut = out + (isB ? OO_ALB : OO_AL) + ((size_t)b*TOUT_ + t)*T;

        float* ah_l = dlds;            // 1024
        float* pqp  = dlds + 1024;     // 512
        float* pq_s = dlds + 1536;     // 128
        float* awp0 = dlds + 1664;     // 208
        float* awp1 = dlds + 1872;     // 208
        float* cw_s = dlds + 2080;     // 1984
        float* vv   = dlds + 4064;     // 128
        float* fmT  = dlds + 4192;     // 5376
        float* ep_s = dlds + 9568;     // 336
        float* wl_s = dlds + 9904;     // 168
        float* smx  = dlds + 10072;    // 2

        // recompute h(t) for this batch from gates (read-only on c_old)
        {
          const float* g  = ws + (isB ? o_gab : o_ga);
          const float* bb = isB ? ab_b : a_b;
          const float* cst = ws + (isB ? o_acb : o_ac) + (size_t)((t+1)&1)*16384;
          for (int u = tid; u < 1024; u += 512) {
            float gi = g[(size_t)u*16 + b]          + bb[u];
            float gf = g[(size_t)(1024+u)*16 + b]   + bb[1024+u];
            float gg = g[(size_t)(2048+u)*16 + b]   + bb[2048+u];
            float go = g[(size_t)(3072+u)*16 + b]   + bb[3072+u];
            float co = cst[u*16 + b];
            float cn = sigf(gf)*co + sigf(gi)*tanhf(gg);
            ah_l[u] = sigf(go)*tanhf(cn);
          }
        }
        for (int i = tid; i < NF_*2*KCV_; i += 512) cw_s[i] = convW[i];
        for (int i = tid; i < 128; i += 512) vv[i] = vW[i];
        for (int i = tid; i < T + 30; i += 512) {
          bool in = (i >= 15) && (i < T + 15);
          awp0[i] = in ? awS[i-15] : 0.f;
          awp1[i] = in ? awcS[i-15] : 0.f;
        }
        __syncthreads();
        {
          int a = tid & 127, hf = tid >> 7;
          float acc2 = 0;
          for (int k = hf*256; k < hf*256 + 256; ++k) acc2 = fmaf(qWT[(size_t)k*128 + a], ah_l[k], acc2);
          pqp[hf*128 + a] = acc2;
        }
        __syncthreads();
        if (tid < 128) pq_s[tid] = pqp[tid] + pqp[128+tid] + pqp[256+tid] + pqp[384+tid];
        __syncthreads();
        for (int idx = tid; idx < T*NF_; idx += 512) {
          int tt = idx >> 5, f = idx & 31;
          const float* c0 = cw_s + f*62;
          float s = 0;
#pragma unroll
          for (int kk = 0; kk < 31; ++kk)
            s = fmaf(awp0[tt+kk], c0[kk], fmaf(awp1[tt+kk], c0[31+kk], s));
          fmT[tt*32 + f] = s;
        }
        __syncthreads();
        {
          int a = tid & 127;
          float la[32];
#pragma unroll
          for (int f = 0; f < 32; ++f) la[f] = locW[a*32 + f];
          float pqr = pq_s[a], vr = vv[a];
          for (int idx = tid; idx < T*128; idx += 512) {
            int tt = idx >> 7;
            float pl = 0;
#pragma unroll
            for (int f = 0; f < 32; ++f) pl = fmaf(fmT[tt*32 + f], la[f], pl);
            float s = vr * tanhf(pqr + pl + pmemB[((size_t)b*T + tt)*128 + a]);
#pragma unroll
            for (int off = 1; off < 64; off <<= 1) s += __shfl_xor(s, off);
            if ((tid & 63) == 0) ep_s[tt*2 + ((idx >> 6) & 1)] = s;
          }
        }
        __syncthreads();
        if (tid < 64) {
          float m = -1e30f;
          for (int i = tid; i < T; i += 64) m = fmaxf(m, ep_s[2*i] + ep_s[2*i+1]);
#pragma unroll
          for (int off = 1; off < 64; off <<= 1) m = fmaxf(m, __shfl_xor(m, off));
          float ssum = 0;
          for (int i = tid; i < T; i += 64) ssum += expf(ep_s[2*i] + ep_s[2*i+1] - m);
#pragma unroll
          for (int off = 1; off < 64; off <<= 1) ssum += __shfl_xor(ssum, off);
          if (tid == 0) { smx[0] = m; smx[1] = 1.f / ssum; }
        }
        __syncthreads();
        for (int i = tid; i < T; i += 512) {
          float wv2 = expf(ep_s[2*i] + ep_s[2*i+1] - smx[0]) * smx[1];
          wl_s[i] = wv2;
          awS[i] = wv2;
          awcS[i] += wv2;
          alOut[i] = wv2;
        }
        __syncthreads();
        {
          float a0 = 0, a1 = 0, a2 = 0, a3 = 0;
          const float* mb = mem + (size_t)b*T*512 + tid;
          int tt = 0;
          for (; tt + 4 <= T; tt += 4) {
            a0 = fmaf(wl_s[tt],   mb[(size_t)tt*512],     a0);
            a1 = fmaf(wl_s[tt+1], mb[(size_t)(tt+1)*512], a1);
            a2 = fmaf(wl_s[tt+2], mb[(size_t)(tt+2)*512], a2);
            a3 = fmaf(wl_s[tt+3], mb[(size_t)(tt+3)*512], a3);
          }
          for (; tt < T; ++tt) a0 = fmaf(wl_s[tt], mb[(size_t)tt*512], a0);
          float acc2 = (a0 + a1) + (a2 + a3);
          ctxS[tid] = acc2;
          ctxAll[tid] = acc2;
        }
      }
    } else if (bid < 160) {
      int gid = (bid - 32)*512 + tid;     // [0, 65536)
      if (gid < 32768) {
        if (t < TOUT_) {   // arnn/arnnb pointwise (canonical write)
          int L = gid >> 14, rem = gid & 16383;
          int u = rem >> 4, b = rem & 15;
          const float* g  = ws + (L ? o_gab : o_ga);
          const float* bb = L ? ab_b : a_b;
          float* cst = ws + (L ? o_acb : o_ac);
          float* h   = ws + (L ? o_ahb : o_ah) + (size_t)(t&1)*16384;
          float gi = g[(size_t)u*16 + b]        + bb[u];
          float gf = g[(size_t)(1024+u)*16 + b] + bb[1024+u];
          float gg = g[(size_t)(2048+u)*16 + b] + bb[2048+u];
          float go = g[(size_t)(3072+u)*16 + b] + bb[3072+u];
          float co = cst[(size_t)((t+1)&1)*16384 + u*16 + b];
          float cn = sigf(gf)*co + sigf(gi)*tanhf(gg);
          float hn = sigf(go)*tanhf(cn);
          cst[(size_t)(t&1)*16384 + u*16 + b] = cn;
          h[b*1024 + u] = hn;
        }
      } else {
        if (t >= 1) {      // drnn/drnnb (t-1) pointwise
          int g2 = gid - 32768;
          int L = g2 >> 14, rem = g2 & 16383;
          int u = rem >> 4, b = rem & 15;
          const float* g  = ws + (L ? o_gdb : o_gd);
          const float* bb = L ? db_b : d_b;
          float* h  = ws + (L ? o_dhb : o_dh);
          float* cc = ws + (L ? o_dcb : o_dc);
          float gi = g[(size_t)u*16 + b]        + bb[u];
          float gf = g[(size_t)(1024+u)*16 + b] + bb[1024+u];
          float gg = g[(size_t)(2048+u)*16 + b] + bb[2048+u];
          float go = g[(size_t)(3072+u)*16 + b] + bb[3072+u];
          float co = cc[u*16 + b];
          float cn = sigf(gf)*co + sigf(gi)*tanhf(gg);
          float hn = sigf(go)*tanhf(cn);
          cc[u*16 + b] = cn;
          h[b*1024 + u] = hn;
          if (L == 0) ws[o_dhall + ((size_t)(t-1)*16 + b)*1024 + u] = hn;
        }
      }
    }
    gridbar(bflags, bgen, ++bcnt);
  }
}

// ================= epilog: batched projection + gate =================
__global__ __launch_bounds__(512) void k_proj(
    const float* __restrict__ pw, const float* __restrict__ pb,
    const float* __restrict__ gw, const float* __restrict__ gb,
    const float* __restrict__ ws, float* __restrict__ out)
{
  int t = blockIdx.x, tid = threadIdx.x;
  for (int o = tid; o < 16*81; o += 512) {
    int b = o / 81, j = o % 81;
    const float* wrow = (j < 80) ? (pw + (size_t)j*2048) : gw;
    const float* xd  = ws + o_dhall   + ((size_t)t*16 + b)*1024;
    const float* xc  = ws + o_ctxall  + ((size_t)t*16 + b)*512;
    const float* xcb = ws + o_ctxball + ((size_t)t*16 + b)*512;
    float acc = dotseg(wrow, xd, 1024) + dotseg(wrow + 1024, xc, 512)
              + dotseg(wrow + 1536, xcb, 512) + ((j < 80) ? pb[j] : gb[0]);
    if (j < 80) out[OO_MEL + ((size_t)b*80 + j)*200 + t] = acc;
    else        out[OO_GATE + (size_t)b*200 + t] = acc;
  }
}

extern "C" void kernel_launch(void* const* d_in, const int* in_sizes, int n_in,
                              void* d_out, int out_size, void* d_ws, size_t ws_size,
                              hipStream_t stream) {
  (void)in_sizes; (void)n_in; (void)out_size;
  const float* memory     = (const float*)d_in[0];
  const float* embeddings = (const float*)d_in[1];
  const float* dec      = (const float*)d_in[2];
  const float* pw1      = (const float*)d_in[3];
  const float* pw2      = (const float*)d_in[4];
  const float* pbw1     = (const float*)d_in[5];
  const float* pbw2     = (const float*)d_in[6];
  const float* a_wih    = (const float*)d_in[7];
  const float* a_whh    = (const float*)d_in[8];
  const float* a_b      = (const float*)d_in[9];
  const float* ab_wih   = (const float*)d_in[10];
  const float* ab_whh   = (const float*)d_in[11];
  const float* ab_b     = (const float*)d_in[12];
  const float* a_q      = (const float*)d_in[13];
  const float* a_m      = (const float*)d_in[14];
  const float* a_conv   = (const float*)d_in[15];
  const float* a_loc    = (const float*)d_in[16];
  const float* a_v      = (const float*)d_in[17];
  const float* ab_q     = (const float*)d_in[18];
  const float* ab_m     = (const float*)d_in[19];
  const float* ab_conv  = (const float*)d_in[20];
  const float* ab_loc   = (const float*)d_in[21];
  const float* ab_v     = (const float*)d_in[22];
  const float* d_wih    = (const float*)d_in[23];
  const float* d_whh    = (const float*)d_in[24];
  const float* d_b      = (const float*)d_in[25];
  const float* db_wih   = (const float*)d_in[26];
  const float* db_whh   = (const float*)d_in[27];
  const float* db_b     = (const float*)d_in[28];
  const float* proj_w   = (const float*)d_in[29];
  const float* proj_b   = (const float*)d_in[30];
  const float* gate_w   = (const float*)d_in[31];
  const float* gate_b   = (const float*)d_in[32];
  float* ws  = (float*)d_ws;
  float* out = (float*)d_out;

  int packed = (ws_size >= o_pkend * sizeof(float)) ? 1 : 0;

  k_prolog<<<dim3(987), dim3(256), 0, stream>>>(dec, pw1, pw2, pbw1, pbw2,
      memory, embeddings, a_m, ab_m, a_q, ab_q,
      a_wih, a_whh, ab_wih, ab_whh, d_wih, d_whh, db_wih, db_whh, packed, ws);

  void* args[] = {
    (void*)&memory, (void*)&embeddings,
    (void*)&a_wih, (void*)&a_whh, (void*)&a_b,
    (void*)&ab_wih, (void*)&ab_whh, (void*)&ab_b,
    (void*)&d_wih, (void*)&d_whh, (void*)&d_b,
    (void*)&db_wih, (void*)&db_whh, (void*)&db_b,
    (void*)&a_conv, (void*)&a_loc, (void*)&a_v,
    (void*)&ab_conv, (void*)&ab_loc, (void*)&ab_v,
    (void*)&packed, (void*)&ws, (void*)&out
  };
  hipLaunchCooperativeKernel(reinterpret_cast<void*>(&k_persist),
                             dim3(256), dim3(512), args, 0, stream);

  k_proj<<<dim3(200), dim3(512), 0, stream>>>(proj_w, proj_b, gate_w, gate_b, ws, out);
}